// Round 1
// baseline (609.745 us; speedup 1.0000x reference)
//
#include <hip/hip_runtime.h>

// Word2MatEncoder: out[b] = prod_{s=0..63} table[sent[b,s]]  (28x28 fp32 chain)
//
// Mapping: 7 lanes per matrix-chain task, each lane owns 4 rows of the running
// product in registers (row i of the product depends only on row i of cur).
// The right-hand matrix M is staged in LDS per task-slot (9 slots/wave,
// stride 788 floats: 16B-aligned + bank-spread). Chain split into P=4
// segments of 16 (associativity) for parallelism; two pairwise combine
// kernels finish the product. fp32 throughout (no fp32 MFMA on CDNA4; bf16
// rounding would compound over 63 chained products).

#define D 28
#define EMB 784
#define SEQ 64
#define NITEMS 2048
#define LPI 7          // lanes per task
#define IPW 9          // tasks (slots) per 64-lane wave (63 lanes active)
#define RPL 4          // rows of the product owned per lane
#define LDS_STRIDE 788 // floats per slot buffer: 784 padded (16B aligned, banks spread)

__device__ __forceinline__ void mat_mul(const float* __restrict__ B,
                                        float (&cur)[RPL][D],
                                        float (&acc)[RPL][D]) {
  // acc = cur @ B   (B row-major [k][j] in LDS)
  // k = 0 initializes acc (saves zero-init movs)
  {
#pragma unroll
    for (int jv = 0; jv < 7; ++jv) {
      float4 m = *(const float4*)(B + 4 * jv);
#pragma unroll
      for (int r = 0; r < RPL; ++r) {
        float a = cur[r][0];
        acc[r][4 * jv + 0] = a * m.x;
        acc[r][4 * jv + 1] = a * m.y;
        acc[r][4 * jv + 2] = a * m.z;
        acc[r][4 * jv + 3] = a * m.w;
      }
    }
  }
  // full unroll: cur[r][k] must be constant-indexed to stay in VGPRs
#pragma unroll
  for (int k = 1; k < D; ++k) {
#pragma unroll
    for (int jv = 0; jv < 7; ++jv) {
      float4 m = *(const float4*)(B + k * D + 4 * jv);
#pragma unroll
      for (int r = 0; r < RPL; ++r) {
        float a = cur[r][k];
        acc[r][4 * jv + 0] = fmaf(a, m.x, acc[r][4 * jv + 0]);
        acc[r][4 * jv + 1] = fmaf(a, m.y, acc[r][4 * jv + 1]);
        acc[r][4 * jv + 2] = fmaf(a, m.z, acc[r][4 * jv + 2]);
        acc[r][4 * jv + 3] = fmaf(a, m.w, acc[r][4 * jv + 3]);
      }
    }
  }
}

// Product of SEG_LEN consecutive matrices of one chain segment.
// dst[task] (784 floats) = table[sp[0]] @ table[sp[1]] @ ... @ table[sp[SEG_LEN-1]]
template <int SEG_LEN, int PSEG>
__global__ __launch_bounds__(64, 1) void chain_kernel(
    const float* __restrict__ table, const int* __restrict__ sent,
    float* __restrict__ dst, int ntask) {
  __shared__ __align__(16) float lds[IPW * LDS_STRIDE];

  const int lane = threadIdx.x;
  int slot = lane / LPI;
  int rl = lane - slot * LPI;
  if (slot >= IPW) { slot = IPW - 1; rl = LPI - 1; }  // lane 63 duplicates lane 62 (benign)
  int task = blockIdx.x * IPW + slot;
  if (task >= ntask) task = ntask - 1;  // tail blocks duplicate last task (same values)

  const int item = task / PSEG;
  const int seg = task - item * PSEG;
  const int* sp = sent + item * SEQ + seg * SEG_LEN;
  float* myLds = lds + slot * LDS_STRIDE;

  float cur[RPL][D], acc[RPL][D];

  // cur = first matrix's rows (this lane owns rows rl*4 .. rl*4+3)
  {
    const float* m0 = table + (size_t)sp[0] * EMB;
#pragma unroll
    for (int r = 0; r < RPL; ++r) {
      const float* rp = m0 + (rl * RPL + r) * D;
#pragma unroll
      for (int jv = 0; jv < 7; ++jv) {
        float4 v = *(const float4*)(rp + 4 * jv);
        cur[r][4 * jv + 0] = v.x;
        cur[r][4 * jv + 1] = v.y;
        cur[r][4 * jv + 2] = v.z;
        cur[r][4 * jv + 3] = v.w;
      }
    }
  }

  // prefetch next matrix into registers (196 float4 / 7 lanes = 28 each)
  float4 pf[28];
  {
    const float* m1 = table + (size_t)sp[1] * EMB;
#pragma unroll
    for (int i = 0; i < 28; ++i) pf[i] = *(const float4*)(m1 + 4 * (rl + 7 * i));
  }

#pragma unroll 1
  for (int s = 1; s < SEG_LEN; ++s) {
    // commit prefetched matrix to this slot's LDS buffer
#pragma unroll
    for (int i = 0; i < 28; ++i) *(float4*)(myLds + 4 * (rl + 7 * i)) = pf[i];
    __syncthreads();
    // issue prefetch of the matrix after next (consumed next iteration)
    if (s + 1 < SEG_LEN) {
      const float* mn = table + (size_t)sp[s + 1] * EMB;
#pragma unroll
      for (int i = 0; i < 28; ++i) pf[i] = *(const float4*)(mn + 4 * (rl + 7 * i));
    }
    mat_mul(myLds, cur, acc);
#pragma unroll
    for (int r = 0; r < RPL; ++r)
#pragma unroll
      for (int j = 0; j < D; ++j) cur[r][j] = acc[r][j];
    __syncthreads();  // all slot lanes done reading before next overwrite
  }

  // store
  {
    float* op = dst + (size_t)task * EMB;
#pragma unroll
    for (int r = 0; r < RPL; ++r) {
      float* rp = op + (rl * RPL + r) * D;
#pragma unroll
      for (int jv = 0; jv < 7; ++jv) {
        float4 v = make_float4(cur[r][4 * jv + 0], cur[r][4 * jv + 1],
                               cur[r][4 * jv + 2], cur[r][4 * jv + 3]);
        *(float4*)(rp + 4 * jv) = v;
      }
    }
  }
}

// D0[task] = A0[task] @ B0[task]; strides in floats. In-place on A is safe:
// each lane reads only its own 4 rows of A into registers before storing.
__global__ __launch_bounds__(64, 1) void combine_kernel(
    const float* __restrict__ A0, const float* __restrict__ B0,
    float* __restrict__ D0, int strideA, int strideB, int strideD, int ntask) {
  __shared__ __align__(16) float lds[IPW * LDS_STRIDE];

  const int lane = threadIdx.x;
  int slot = lane / LPI;
  int rl = lane - slot * LPI;
  if (slot >= IPW) { slot = IPW - 1; rl = LPI - 1; }
  int task = blockIdx.x * IPW + slot;
  if (task >= ntask) task = ntask - 1;

  const float* A = A0 + (size_t)task * strideA;
  const float* Bg = B0 + (size_t)task * strideB;
  float* Dst = D0 + (size_t)task * strideD;
  float* myLds = lds + slot * LDS_STRIDE;

  float cur[RPL][D], acc[RPL][D];
#pragma unroll
  for (int r = 0; r < RPL; ++r) {
    const float* rp = A + (rl * RPL + r) * D;
#pragma unroll
    for (int jv = 0; jv < 7; ++jv) {
      float4 v = *(const float4*)(rp + 4 * jv);
      cur[r][4 * jv + 0] = v.x;
      cur[r][4 * jv + 1] = v.y;
      cur[r][4 * jv + 2] = v.z;
      cur[r][4 * jv + 3] = v.w;
    }
  }
#pragma unroll
  for (int i = 0; i < 28; ++i) {
    float4 v = *(const float4*)(Bg + 4 * (rl + 7 * i));
    *(float4*)(myLds + 4 * (rl + 7 * i)) = v;
  }
  __syncthreads();
  mat_mul(myLds, cur, acc);
#pragma unroll
  for (int r = 0; r < RPL; ++r) {
    float* rp = Dst + (rl * RPL + r) * D;
#pragma unroll
    for (int jv = 0; jv < 7; ++jv) {
      float4 v = make_float4(acc[r][4 * jv + 0], acc[r][4 * jv + 1],
                             acc[r][4 * jv + 2], acc[r][4 * jv + 3]);
      *(float4*)(rp + 4 * jv) = v;
    }
  }
}

extern "C" void kernel_launch(void* const* d_in, const int* in_sizes, int n_in,
                              void* d_out, int out_size, void* d_ws, size_t ws_size,
                              hipStream_t stream) {
  const float* table = (const float*)d_in[0];
  const int* sent = (const int*)d_in[1];
  float* out = (float*)d_out;

  const size_t need = (size_t)NITEMS * 4 * EMB * sizeof(float);  // 25.7 MB
  if (ws_size >= need) {
    float* p = (float*)d_ws;
    // phase 1: 4 segments of 16 per item -> 8192 partial products
    const int ntask1 = NITEMS * 4;
    chain_kernel<16, 4><<<(ntask1 + IPW - 1) / IPW, 64, 0, stream>>>(table, sent, p, ntask1);
    // phase 2a: pairwise combine 8192 -> 4096 (in place over left operand)
    combine_kernel<<<(NITEMS * 2 + IPW - 1) / IPW, 64, 0, stream>>>(
        p, p + EMB, p, 2 * EMB, 2 * EMB, 2 * EMB, NITEMS * 2);
    // phase 2b: final combine 4096 -> 2048 into d_out
    combine_kernel<<<(NITEMS + IPW - 1) / IPW, 64, 0, stream>>>(
        p, p + 2 * EMB, out, 4 * EMB, 4 * EMB, EMB, NITEMS);
  } else {
    // fallback: direct 64-long chain per item straight into d_out
    chain_kernel<64, 1><<<(NITEMS + IPW - 1) / IPW, 64, 0, stream>>>(table, sent, out, NITEMS);
  }
}

// Round 2
// 345.546 us; speedup vs baseline: 1.7646x; 1.7646x over previous
//
#include <hip/hip_runtime.h>

// Word2MatEncoder: out[b] = prod_{s=0..63} table[sent[b,s]]  (28x28 fp32 chain)
//
// R2: kill register spills. 14 lanes per task, 2 rows of the running product
// per lane (cur 56 + acc 56 + pf 56 regs ~= 170 total, fits 256 with no
// scratch). 4 tasks per 64-lane wave (lanes 56-63 duplicate lane 55, benign).
// Right-hand matrix staged in LDS (stride 788 floats -> slot bank offsets
// {0,20,8,28}: broadcast reads conflict-free). Chain split into P=4 segments
// of 16 (associativity); one fused combine kernel chains the 4 partials.
// fp32 throughout (no fp32 MFMA on CDNA4; bf16 would compound error over 63
// chained products).

#define D 28
#define EMB 784
#define SEQ 64
#define NITEMS 2048
#define LPI 14         // lanes per task
#define IPW 4          // tasks (slots) per 64-lane wave (56 lanes active)
#define RPL 2          // rows of the product owned per lane
#define PFN 14         // float4 staged per lane per matrix (196 / LPI)
#define LDS_STRIDE 788 // floats per slot buffer (784 padded; banks spread 20s%32)

__device__ __forceinline__ void mat_mul(const float* __restrict__ B,
                                        float (&cur)[RPL][D],
                                        float (&acc)[RPL][D]) {
  // acc = cur @ B   (B row-major [k][j] in LDS); k = 0 initializes acc
  {
#pragma unroll
    for (int jv = 0; jv < 7; ++jv) {
      float4 m = *(const float4*)(B + 4 * jv);
#pragma unroll
      for (int r = 0; r < RPL; ++r) {
        float a = cur[r][0];
        acc[r][4 * jv + 0] = a * m.x;
        acc[r][4 * jv + 1] = a * m.y;
        acc[r][4 * jv + 2] = a * m.z;
        acc[r][4 * jv + 3] = a * m.w;
      }
    }
  }
#pragma unroll
  for (int k = 1; k < D; ++k) {
#pragma unroll
    for (int jv = 0; jv < 7; ++jv) {
      float4 m = *(const float4*)(B + k * D + 4 * jv);
#pragma unroll
      for (int r = 0; r < RPL; ++r) {
        float a = cur[r][k];
        acc[r][4 * jv + 0] = fmaf(a, m.x, acc[r][4 * jv + 0]);
        acc[r][4 * jv + 1] = fmaf(a, m.y, acc[r][4 * jv + 1]);
        acc[r][4 * jv + 2] = fmaf(a, m.z, acc[r][4 * jv + 2]);
        acc[r][4 * jv + 3] = fmaf(a, m.w, acc[r][4 * jv + 3]);
      }
    }
  }
}

// Product of SEG_LEN consecutive matrices.
// GATHER=true : matrices are table[sp[s]] with sp = sent + item*SEQ + seg*SEG_LEN
// GATHER=false: matrices are src + (task*SEG_LEN + s)*EMB   (dense partials)
template <int SEG_LEN, int PSEG, bool GATHER>
__global__ __launch_bounds__(64, 1) void chain_kernel(
    const float* __restrict__ src, const int* __restrict__ sent,
    float* __restrict__ dst, int ntask) {
  __shared__ __align__(16) float lds[IPW * LDS_STRIDE];

  const int lane = threadIdx.x;
  int slot = lane / LPI;
  int rl = lane - slot * LPI;
  if (slot >= IPW) { slot = IPW - 1; rl = LPI - 1; }  // lanes 56-63 mirror lane 55
  int task = blockIdx.x * IPW + slot;
  if (task >= ntask) task = ntask - 1;  // tail duplicates (same values, benign)

  const int* sp = nullptr;
  if (GATHER) {
    const int item = task / PSEG;
    const int seg = task - item * PSEG;
    sp = sent + item * SEQ + seg * SEG_LEN;
  }
  float* myLds = lds + slot * LDS_STRIDE;

  auto mat_ptr = [&](int s) -> const float* {
    if (GATHER) return src + (size_t)sp[s] * EMB;
    return src + ((size_t)task * SEG_LEN + s) * EMB;
  };

  float cur[RPL][D], acc[RPL][D];

  // cur = first matrix's rows (this lane owns rows rl*RPL .. rl*RPL+RPL-1)
  {
    const float* m0 = mat_ptr(0);
#pragma unroll
    for (int r = 0; r < RPL; ++r) {
      const float* rp = m0 + (rl * RPL + r) * D;
#pragma unroll
      for (int jv = 0; jv < 7; ++jv) {
        float4 v = *(const float4*)(rp + 4 * jv);
        cur[r][4 * jv + 0] = v.x;
        cur[r][4 * jv + 1] = v.y;
        cur[r][4 * jv + 2] = v.z;
        cur[r][4 * jv + 3] = v.w;
      }
    }
  }

  // prefetch next matrix into registers (196 float4 / 14 lanes = 14 each)
  float4 pf[PFN];
  {
    const float* m1 = mat_ptr(1);
#pragma unroll
    for (int i = 0; i < PFN; ++i) pf[i] = *(const float4*)(m1 + 4 * (rl + LPI * i));
  }

#pragma unroll 1
  for (int s = 1; s < SEG_LEN; ++s) {
    // commit prefetched matrix to this slot's LDS buffer
#pragma unroll
    for (int i = 0; i < PFN; ++i) *(float4*)(myLds + 4 * (rl + LPI * i)) = pf[i];
    __syncthreads();
    // issue prefetch of the matrix after next (consumed next iteration)
    if (s + 1 < SEG_LEN) {
      const float* mn = mat_ptr(s + 1);
#pragma unroll
      for (int i = 0; i < PFN; ++i) pf[i] = *(const float4*)(mn + 4 * (rl + LPI * i));
    }
    mat_mul(myLds, cur, acc);
#pragma unroll
    for (int r = 0; r < RPL; ++r)
#pragma unroll
      for (int j = 0; j < D; ++j) cur[r][j] = acc[r][j];
    __syncthreads();  // all slot lanes done reading before next overwrite
  }

  // store
  {
    float* op = dst + (size_t)task * EMB;
#pragma unroll
    for (int r = 0; r < RPL; ++r) {
      float* rp = op + (rl * RPL + r) * D;
#pragma unroll
      for (int jv = 0; jv < 7; ++jv) {
        float4 v = make_float4(cur[r][4 * jv + 0], cur[r][4 * jv + 1],
                               cur[r][4 * jv + 2], cur[r][4 * jv + 3]);
        *(float4*)(rp + 4 * jv) = v;
      }
    }
  }
}

extern "C" void kernel_launch(void* const* d_in, const int* in_sizes, int n_in,
                              void* d_out, int out_size, void* d_ws, size_t ws_size,
                              hipStream_t stream) {
  const float* table = (const float*)d_in[0];
  const int* sent = (const int*)d_in[1];
  float* out = (float*)d_out;

  const size_t need = (size_t)NITEMS * 4 * EMB * sizeof(float);  // 25.7 MB
  if (ws_size >= need) {
    float* p = (float*)d_ws;
    // phase 1: 4 segments of 16 per item -> 8192 partial products (contiguous per item)
    const int ntask1 = NITEMS * 4;
    chain_kernel<16, 4, true><<<(ntask1 + IPW - 1) / IPW, 64, 0, stream>>>(
        table, sent, p, ntask1);
    // phase 2: chain each item's 4 partials -> d_out (fused combine)
    chain_kernel<4, 1, false><<<(NITEMS + IPW - 1) / IPW, 64, 0, stream>>>(
        p, nullptr, out, NITEMS);
  } else {
    // fallback: direct 64-long chain per item straight into d_out
    chain_kernel<64, 1, true><<<(NITEMS + IPW - 1) / IPW, 64, 0, stream>>>(
        table, sent, out, NITEMS);
  }
}